// Round 14
// baseline (162.554 us; speedup 1.0000x reference)
//
#include <hip/hip_runtime.h>
#include <hip/hip_bf16.h>

#define B_ 4
#define L_ 1024
#define H_ 12
#define DK_ 64
#define FEA_ 768
#define MASKV (-32767.0f)

typedef __attribute__((ext_vector_type(8))) short bf16x8;
typedef __attribute__((ext_vector_type(4))) short s16x4;
typedef __attribute__((ext_vector_type(4))) float f32x4;
typedef unsigned int u32;
typedef unsigned long long u64;

__device__ inline short f2bf(float x) {
  __hip_bfloat16 h = __float2bfloat16(x);   // HW cvt, RNE
  return __builtin_bit_cast(short, h);
}

// sizes (floats)
#define SZX  (4 * 1024 * 768)      // qx/kx/vx each: 3145728
#define SZW  (768 * 768)           // each W: 589824

// ---------------------------------------------------------------------------
// fp32 -> bf16 convert pass (qx,kx,vx,Wq,Wk,Wv) + maskPAD bit-pack.
// Packed mask: u64 per (row, 64-key tile): bit k = maskPAD[...][k]!=0,
// built wave-coherently via __ballot (64 contiguous ints -> 1 u64).
// ---------------------------------------------------------------------------
__global__ __launch_bounds__(256) void k_cvt(
    const float* __restrict__ qx, const float* __restrict__ kx,
    const float* __restrict__ vx,
    const float* __restrict__ Wq, const float* __restrict__ Wk,
    const float* __restrict__ Wv,
    const int* __restrict__ maskPAD,
    unsigned short* __restrict__ dst, u64* __restrict__ maskPk)
{
  const size_t SZX4 = SZX / 4, SZW4 = SZW / 4;
  const size_t total4 = 3 * SZX4 + 3 * SZW4;
  for (size_t i4 = (size_t)blockIdx.x * 256 + threadIdx.x; i4 < total4;
       i4 += (size_t)gridDim.x * 256) {
    const float* src; size_t o4; size_t db;
    if (i4 < SZX4)               { src = qx; o4 = i4;               db = 0; }
    else if (i4 < 2 * SZX4)      { src = kx; o4 = i4 - SZX4;        db = (size_t)SZX; }
    else if (i4 < 3 * SZX4)      { src = vx; o4 = i4 - 2 * SZX4;    db = 2 * (size_t)SZX; }
    else if (i4 < 3 * SZX4 + SZW4)     { src = Wq; o4 = i4 - 3 * SZX4;            db = 3 * (size_t)SZX; }
    else if (i4 < 3 * SZX4 + 2 * SZW4) { src = Wk; o4 = i4 - 3 * SZX4 - SZW4;     db = 3 * (size_t)SZX + SZW; }
    else                               { src = Wv; o4 = i4 - 3 * SZX4 - 2 * SZW4; db = 3 * (size_t)SZX + 2 * (size_t)SZW; }
    float4 v = ((const float4*)src)[o4];
    s16x4 r = {f2bf(v.x), f2bf(v.y), f2bf(v.z), f2bf(v.w)};
    *(s16x4*)(dst + db + o4 * 4) = r;
  }

  // mask bit-pack: 4.19M ints -> 65536 u64
  const size_t NM = (size_t)B_ * L_ * L_;
  const size_t wgid = ((size_t)blockIdx.x * 256 + threadIdx.x) >> 6;
  const size_t nwaves = ((size_t)gridDim.x * 256) >> 6;
  const int ln = threadIdx.x & 63;
  for (size_t base = wgid * 64; base < NM; base += nwaves * 64) {
    int m = maskPAD[base + ln];
    u64 bits = __ballot(m != 0);
    if (ln == 0) maskPk[base >> 6] = bits;
  }
}

// ---------------------------------------------------------------------------
// Wo fp32 -> bf16, launched AFTER k_attn; dst aliases the then-dead Qb region.
// ---------------------------------------------------------------------------
__global__ __launch_bounds__(256) void k_cvt2(
    const float* __restrict__ Wo, unsigned short* __restrict__ dst)
{
  size_t i4 = (size_t)blockIdx.x * 256 + threadIdx.x;
  if (i4 < (size_t)SZW / 4) {
    float4 v = ((const float4*)Wo)[i4];
    s16x4 r = {f2bf(v.x), f2bf(v.y), f2bf(v.z), f2bf(v.w)};
    *(s16x4*)(dst + i4 * 4) = r;
  }
}

// ---------------------------------------------------------------------------
// QKV projection (pure bf16, verified R11/R12).
// ---------------------------------------------------------------------------
__global__ __launch_bounds__(256) void k_proj(
    const unsigned short* __restrict__ qxb, const unsigned short* __restrict__ kxb,
    const unsigned short* __restrict__ vxb,
    const unsigned short* __restrict__ Wqb, const unsigned short* __restrict__ Wkb,
    const unsigned short* __restrict__ Wvb,
    const float* __restrict__ bq, const float* __restrict__ bk,
    const float* __restrict__ bv,
    unsigned short* __restrict__ Qb, unsigned short* __restrict__ Kb,
    unsigned short* __restrict__ Vt)
{
  __shared__ short lA[2][64 * 64];
  __shared__ short lB[2][64 * 64];

  const int which = blockIdx.z;
  const unsigned short* __restrict__ Ab = (which == 0) ? qxb : (which == 1) ? kxb : vxb;
  const unsigned short* __restrict__ Wb = (which == 0) ? Wqb : (which == 1) ? Wkb : Wvb;
  const float* __restrict__ bias = (which == 0) ? bq : (which == 1) ? bk : bv;

  const int tid = threadIdx.x;
  const int lane = tid & 63;
  const int wid = tid >> 6;
  const int wr = wid >> 1, wc = wid & 1;
  const int m0 = blockIdx.x * 64;
  const int n0 = blockIdx.y * 64;
  const int g = lane >> 4, qc = lane & 15;
  const int srow = lane >> 3;
  const int spos = lane & 7;

#define PSTAGE(buf, ktof)                                                      \
  {                                                                            \
    _Pragma("unroll")                                                          \
    for (int i_ = 0; i_ < 2; i_++) {                                           \
      int r0_ = wid * 16 + i_ * 8;                                             \
      int row_ = r0_ + srow;                                                   \
      int cs_ = spos ^ (row_ & 7);                                             \
      __builtin_amdgcn_global_load_lds(                                        \
          (const __attribute__((address_space(1))) u32*)(Ab +                  \
              (size_t)(m0 + row_) * FEA_ + (ktof) + cs_ * 8),                  \
          (__attribute__((address_space(3))) u32*)&lA[buf][r0_ * 64],          \
          16, 0, 0);                                                           \
      __builtin_amdgcn_global_load_lds(                                        \
          (const __attribute__((address_space(1))) u32*)(Wb +                  \
              (size_t)(n0 + row_) * FEA_ + (ktof) + cs_ * 8),                  \
          (__attribute__((address_space(3))) u32*)&lB[buf][r0_ * 64],          \
          16, 0, 0);                                                           \
    }                                                                          \
  }

  f32x4 acc[2][2];
#pragma unroll
  for (int i = 0; i < 2; i++)
#pragma unroll
    for (int j = 0; j < 2; j++) acc[i][j] = f32x4{0.f, 0.f, 0.f, 0.f};

  PSTAGE(0, 0);
  asm volatile("s_waitcnt vmcnt(0)" ::: "memory");
  __builtin_amdgcn_s_barrier();

  for (int kt = 0; kt < 12; kt++) {
    const int cur = kt & 1, nxt = cur ^ 1;
    if (kt < 11) PSTAGE(nxt, (kt + 1) * 64);
    __builtin_amdgcn_sched_barrier(0);
    __builtin_amdgcn_s_setprio(1);
#pragma unroll
    for (int s = 0; s < 2; s++) {
      bf16x8 af[2], bfr[2];
#pragma unroll
      for (int i = 0; i < 2; i++) {
        int ar = wr * 32 + i * 16 + qc;
        af[i] = *(const bf16x8*)&lA[cur][ar * 64 + (((s * 4 + g) ^ (ar & 7)) << 3)];
        int br = wc * 32 + i * 16 + qc;
        bfr[i] = *(const bf16x8*)&lB[cur][br * 64 + (((s * 4 + g) ^ (br & 7)) << 3)];
      }
#pragma unroll
      for (int i = 0; i < 2; i++)
#pragma unroll
        for (int j = 0; j < 2; j++)
          acc[i][j] = __builtin_amdgcn_mfma_f32_16x16x32_bf16(af[i], bfr[j], acc[i][j], 0, 0, 0);
    }
    __builtin_amdgcn_s_setprio(0);
    asm volatile("s_waitcnt vmcnt(0)" ::: "memory");
    __builtin_amdgcn_s_barrier();
  }

  const int cn0 = n0 + wc * 32;
  float bv2[2];
#pragma unroll
  for (int j = 0; j < 2; j++) bv2[j] = bias[cn0 + j * 16 + qc];

#pragma unroll
  for (int i = 0; i < 2; i++) {
    int m = m0 + wr * 32 + i * 16 + g * 4;
    int bb = m >> 10;
    int l = m & 1023;
#pragma unroll
    for (int j = 0; j < 2; j++) {
      int n = cn0 + j * 16 + qc;
      int hh = n >> 6, d = n & 63;
      if (which == 2) {
        s16x4 vv = {f2bf(acc[i][j][0] + bv2[j]), f2bf(acc[i][j][1] + bv2[j]),
                    f2bf(acc[i][j][2] + bv2[j]), f2bf(acc[i][j][3] + bv2[j])};
        *(s16x4*)&Vt[(((size_t)bb * H_ + hh) * DK_ + d) * L_ + l] = vv;
      } else {
#pragma unroll
        for (int r = 0; r < 4; r++) {
          unsigned short v = (unsigned short)f2bf(acc[i][j][r] + bv2[j]);
          if (which == 0) {
            Qb[(((size_t)bb * H_ + hh) * L_ + (l + r)) * DK_ + d] = v;
          } else {
            Kb[(((size_t)bb * H_ + hh) * L_ + (l + r)) * DK_ + d] = v;
          }
        }
      }
    }
  }
#undef PSTAGE
}

// ---------------------------------------------------------------------------
// Fused attention v10: R13 coalesced layout + BIT-PACKED mask (one u32 per
// 4 rows/lane/tile replaces 4x int4 loads; -195MB logical read stream).
// ---------------------------------------------------------------------------
__global__ __launch_bounds__(256, 3) void k_attn(
    const unsigned short* __restrict__ Qb, const unsigned short* __restrict__ Kb,
    const unsigned short* __restrict__ Vt,
    const float* __restrict__ preScores, const u32* __restrict__ maskPk,
    float* __restrict__ scoresOut, unsigned short* __restrict__ zp)
{
  __shared__ short lK[2][64 * 64];
  __shared__ short lV[2][64 * 64];
  __shared__ float lU[4][1120];

  const int tid = threadIdx.x, lane = tid & 63, wid = tid >> 6;
  const int bi = blockIdx.x;
  const int slot = bi >> 3;
  const int bh_i = (bi & 7) * 6 + (slot >> 4);
  const int qt = slot & 15;
  const int b = bh_i / H_;
  const int h = bh_i % H_;
  const int q0 = qt * 64;
  const int g = lane >> 4, qr = lane & 15;
  const int qrow = q0 + wid * 16 + qr;
  const int rhi = lane >> 4, klo = lane & 15;
  const int rowCg = q0 + wid * 16 + rhi;

  const size_t bh = (size_t)b * H_ + h;
  const unsigned short* __restrict__ Kbh = Kb + bh * L_ * DK_;
  const unsigned short* __restrict__ Vbh = Vt + bh * DK_ * L_;

  float* lSw = &lU[wid][0];
  short* lPw = (short*)&lU[wid][0];
  float* lLw = &lU[wid][1088];

  const int srow = lane >> 3;
  const int spos = lane & 7;

#define STAGE_KV(buf, kv0)                                                     \
  {                                                                            \
    _Pragma("unroll")                                                          \
    for (int i_ = 0; i_ < 2; i_++) {                                           \
      int r0_ = wid * 16 + i_ * 8;                                             \
      int row_ = r0_ + srow;                                                   \
      int cs_ = spos ^ (row_ & 7);                                             \
      __builtin_amdgcn_global_load_lds(                                        \
          (const __attribute__((address_space(1))) u32*)(Kbh +                 \
              (size_t)((kv0) + row_) * DK_ + cs_ * 8),                         \
          (__attribute__((address_space(3))) u32*)&lK[buf][r0_ * 64],          \
          16, 0, 0);                                                           \
      __builtin_amdgcn_global_load_lds(                                        \
          (const __attribute__((address_space(1))) u32*)(Vbh +                 \
              (size_t)row_ * L_ + (kv0) + cs_ * 8),                            \
          (__attribute__((address_space(3))) u32*)&lV[buf][r0_ * 64],          \
          16, 0, 0);                                                           \
    }                                                                          \
  }

  bf16x8 qf[2];
#pragma unroll
  for (int s = 0; s < 2; s++)
    qf[s] = *(const bf16x8*)(Qb + (bh * L_ + qrow) * DK_ + s * 32 + g * 8);

  f32x4 o[4];
#pragma unroll
  for (int i = 0; i < 4; i++) o[i] = f32x4{0.f, 0.f, 0.f, 0.f};
  float psum[4] = {0.f, 0.f, 0.f, 0.f};

  const size_t psCbase = (bh * L_ + rowCg) * L_ + klo * 4;
  // packed mask: u32 index = ((b*1024 + row)*16 + kt)*2 + (klo>>3)
  const size_t mkPbase = (((size_t)b * L_ + rowCg) * 16) * 2 + (klo >> 3);
  const int mshift = (klo & 7) * 4;

  STAGE_KV(0, 0);
  __builtin_amdgcn_sched_barrier(0);
  float4 psn[4];
  u32 mkn[4];
#pragma unroll
  for (int j = 0; j < 4; j++) {
    psn[j] = *(const float4*)(preScores + psCbase + j * 4096);
    mkn[j] = maskPk[mkPbase + j * 128];
  }
  asm volatile("s_waitcnt vmcnt(8)" ::: "memory");
  __builtin_amdgcn_s_barrier();

  for (int kt = 0; kt < 16; kt++) {
    const int kv0 = kt * 64;
    const int cur = kt & 1, nxt = cur ^ 1;

    if (kt < 15) {
      STAGE_KV(nxt, kv0 + 64);
    }
    __builtin_amdgcn_sched_barrier(0);

    float4 psc[4]; u32 mkc[4];
#pragma unroll
    for (int j = 0; j < 4; j++) { psc[j] = psn[j]; mkc[j] = mkn[j]; }
    if (kt < 15) {
#pragma unroll
      for (int j = 0; j < 4; j++) {
        psn[j] = *(const float4*)(preScores + psCbase + kv0 + 64 + j * 4096);
        mkn[j] = maskPk[mkPbase + (kt + 1) * 2 + j * 128];
      }
    }

    // S^T = K . Q^T from LDS (MFMA layout)
    f32x4 st[4];
#pragma unroll
    for (int i = 0; i < 4; i++) st[i] = f32x4{0.f, 0.f, 0.f, 0.f};
    __builtin_amdgcn_s_setprio(1);
#pragma unroll
    for (int s = 0; s < 2; s++) {
#pragma unroll
      for (int i = 0; i < 4; i++) {
        int kr = i * 16 + qr;
        bf16x8 kf = *(const bf16x8*)&lK[cur][kr * 64 + (((s * 4 + g) ^ (kr & 7)) << 3)];
        st[i] = __builtin_amdgcn_mfma_f32_16x16x32_bf16(kf, qf[s], st[i], 0, 0, 0);
      }
    }
    __builtin_amdgcn_s_setprio(0);

    // bridge MFMA layout -> coalesced layout through wave-private LDS
#pragma unroll
    for (int i = 0; i < 4; i++)
      *(f32x4*)&lSw[qr * 68 + i * 16 + g * 4] = st[i];
    f32x4 stc[4];
#pragma unroll
    for (int j = 0; j < 4; j++)
      stc[j] = *(const f32x4*)&lSw[(4 * j + rhi) * 68 + klo * 4];

    // coalesced: scale + ps + packed mask; contiguous scores store; exp;
    // per-row psum; pack p into lP (aliases lS head).
#pragma unroll
    for (int j = 0; j < 4; j++) {
      u32 nib = (mkc[j] >> mshift) & 0xFu;
      float4 sv;
      sv.x = ((nib & 1u) == 0) ? MASKV : stc[j][0] * 0.125f + psc[j].x;
      sv.y = ((nib & 2u) == 0) ? MASKV : stc[j][1] * 0.125f + psc[j].y;
      sv.z = ((nib & 4u) == 0) ? MASKV : stc[j][2] * 0.125f + psc[j].z;
      sv.w = ((nib & 8u) == 0) ? MASKV : stc[j][3] * 0.125f + psc[j].w;
      *(float4*)(scoresOut + psCbase + kv0 + j * 4096) = sv;
      float p0 = __expf(sv.x);
      float p1 = __expf(sv.y);
      float p2 = __expf(sv.z);
      float p3 = __expf(sv.w);
      psum[j] += (p0 + p1) + (p2 + p3);
      s16x4 pw = {f2bf(p0), f2bf(p1), f2bf(p2), f2bf(p3)};
      int rL = 4 * j + rhi;
      int c = klo >> 1, sub = (klo & 1) * 4;
      *(s16x4*)&lPw[rL * 64 + ((c ^ (rL & 7)) << 3) + sub] = pw;
    }

    // O^T += Vt_strip . P^T from LDS
    __builtin_amdgcn_s_setprio(1);
#pragma unroll
    for (int s = 0; s < 2; s++) {
      bf16x8 pf = *(const bf16x8*)&lPw[qr * 64 + (((s * 4 + g) ^ (qr & 7)) << 3)];
#pragma unroll
      for (int i = 0; i < 4; i++) {
        int vr = i * 16 + qr;
        bf16x8 vf = *(const bf16x8*)&lV[cur][vr * 64 + (((s * 4 + g) ^ (vr & 7)) << 3)];
        o[i] = __builtin_amdgcn_mfma_f32_16x16x32_bf16(vf, pf, o[i], 0, 0, 0);
      }
    }
    __builtin_amdgcn_s_setprio(0);

    asm volatile("s_waitcnt vmcnt(12)" ::: "memory");
    __builtin_amdgcn_s_barrier();
  }

  // per-row sums reduce + normalize + write z_pre
#pragma unroll
  for (int j = 0; j < 4; j++) {
    float v = psum[j];
    v += __shfl_xor(v, 1);
    v += __shfl_xor(v, 2);
    v += __shfl_xor(v, 4);
    v += __shfl_xor(v, 8);
    if (klo == 0) lLw[4 * j + rhi] = v;
  }
  float inv = 1.f / lLw[qr];
  size_t zr = ((size_t)b * L_ + qrow) * FEA_ + (size_t)h * DK_;
#pragma unroll
  for (int i = 0; i < 4; i++) {
    s16x4 zw = {f2bf(o[i][0] * inv), f2bf(o[i][1] * inv),
                f2bf(o[i][2] * inv), f2bf(o[i][3] * inv)};
    *(s16x4*)((unsigned short*)zp + zr + i * 16 + g * 4) = zw;
  }
#undef STAGE_KV
}

// ---------------------------------------------------------------------------
// Output projection (pure bf16, verified R12).
// ---------------------------------------------------------------------------
__global__ __launch_bounds__(256) void k_oproj(
    const unsigned short* __restrict__ zp,
    const unsigned short* __restrict__ Wob, const float* __restrict__ bo,
    float* __restrict__ out)
{
  __shared__ short lA[2][64 * 64];
  __shared__ short lB[2][64 * 64];

  const int tid = threadIdx.x;
  const int lane = tid & 63;
  const int wid = tid >> 6;
  const int wr = wid >> 1, wc = wid & 1;
  const int m0 = blockIdx.x * 64;
  const int n0 = blockIdx.y * 64;
  const int g = lane >> 4, qc = lane & 15;
  const int srow = lane >> 3;
  const int spos = lane & 7;

#define OSTAGE(buf, ktof)                                                      \
  {                                                                            \
    _Pragma("unroll")                                                          \
    for (int i_ = 0; i_ < 2; i_++) {                                           \
      int r0_ = wid * 16 + i_ * 8;                                             \
      int row_ = r0_ + srow;                                                   \
      int cs_ = spos ^ (row_ & 7);                                             \
      __builtin_amdgcn_global_load_lds(                                        \
          (const __attribute__((address_space(1))) u32*)(zp +                  \
              (size_t)(m0 + row_) * FEA_ + (ktof) + cs_ * 8),                  \
          (__attribute__((address_space(3))) u32*)&lA[buf][r0_ * 64],          \
          16, 0, 0);                                                           \
      __builtin_amdgcn_global_load_lds(                                        \
          (const __attribute__((address_space(1))) u32*)(Wob +                 \
              (size_t)(n0 + row_) * FEA_ + (ktof) + cs_ * 8),                  \
          (__attribute__((address_space(3))) u32*)&lB[buf][r0_ * 64],          \
          16, 0, 0);                                                           \
    }                                                                          \
  }

  f32x4 acc[2][2];
#pragma unroll
  for (int i = 0; i < 2; i++)
#pragma unroll
    for (int j = 0; j < 2; j++) acc[i][j] = f32x4{0.f, 0.f, 0.f, 0.f};

  OSTAGE(0, 0);
  asm volatile("s_waitcnt vmcnt(0)" ::: "memory");
  __builtin_amdgcn_s_barrier();

  for (int kt = 0; kt < 12; kt++) {
    const int cur = kt & 1, nxt = cur ^ 1;
    if (kt < 11) OSTAGE(nxt, (kt + 1) * 64);
    __builtin_amdgcn_sched_barrier(0);
    __builtin_amdgcn_s_setprio(1);
#pragma unroll
    for (int s = 0; s < 2; s++) {
      bf16x8 af[2], bfr[2];
#pragma unroll
      for (int i = 0; i < 2; i++) {
        int ar = wr * 32 + i * 16 + qc;
        af[i] = *(const bf16x8*)&lA[cur][ar * 64 + (((s * 4 + g) ^ (ar & 7)) << 3)];
        int br = wc * 32 + i * 16 + qc;
        bfr[i] = *(const bf16x8*)&lB[cur][br * 64 + (((s * 4 + g) ^ (br & 7)) << 3)];
      }
#pragma unroll
      for (int i = 0; i < 2; i++)
#pragma unroll
        for (int j = 0; j < 2; j++)
          acc[i][j] = __builtin_amdgcn_mfma_f32_16x16x32_bf16(af[i], bfr[j], acc[i][j], 0, 0, 0);
    }
    __builtin_amdgcn_s_setprio(0);
    asm volatile("s_waitcnt vmcnt(0)" ::: "memory");
    __builtin_amdgcn_s_barrier();
  }

  const int cn0 = n0 + wc * 32;
  float bv2[2];
#pragma unroll
  for (int j = 0; j < 2; j++) bv2[j] = bo[cn0 + j * 16 + qc];

#pragma unroll
  for (int i = 0; i < 2; i++) {
    int m = m0 + wr * 32 + i * 16 + g * 4;
#pragma unroll
    for (int j = 0; j < 2; j++) {
      int n = cn0 + j * 16 + qc;
#pragma unroll
      for (int r = 0; r < 4; r++) {
        out[(size_t)(m + r) * FEA_ + n] = acc[i][j][r] + bv2[j];
      }
    }
  }
#undef OSTAGE
}

extern "C" void kernel_launch(void* const* d_in, const int* in_sizes, int n_in,
                              void* d_out, int out_size, void* d_ws, size_t ws_size,
                              hipStream_t stream) {
  const float* qx = (const float*)d_in[0];
  const float* kx = (const float*)d_in[1];
  const float* vx = (const float*)d_in[2];
  const float* preScores = (const float*)d_in[3];
  const int* maskPAD = (const int*)d_in[4];
  const float* Wq = (const float*)d_in[5];
  const float* bq = (const float*)d_in[6];
  const float* Wk = (const float*)d_in[7];
  const float* bk = (const float*)d_in[8];
  const float* Wv = (const float*)d_in[9];
  const float* bv = (const float*)d_in[10];
  const float* Wo = (const float*)d_in[11];
  const float* bo = (const float*)d_in[12];

  float* z_out = (float*)d_out;
  float* scores_out = z_out + (size_t)B_ * L_ * FEA_;

  unsigned short* Qb = (unsigned short*)d_ws;
  unsigned short* Kb = Qb + (size_t)B_ * H_ * L_ * DK_;
  unsigned short* Vt = Kb + (size_t)B_ * H_ * L_ * DK_;
  unsigned short* zp = Vt + (size_t)B_ * H_ * L_ * DK_;

  // bf16 scratch in scores-region tail (dead once k_proj completes).
  unsigned short* cvtb = (unsigned short*)(scores_out + (50331648 - 5603328));
  const unsigned short* qxb = cvtb;
  const unsigned short* kxb = cvtb + (size_t)SZX;
  const unsigned short* vxb = cvtb + 2 * (size_t)SZX;
  const unsigned short* Wqb = cvtb + 3 * (size_t)SZX;
  const unsigned short* Wkb = cvtb + 3 * (size_t)SZX + (size_t)SZW;
  const unsigned short* Wvb = cvtb + 3 * (size_t)SZX + 2 * (size_t)SZW;

  // packed mask (524KB) lives in z_out region: written by k_cvt, read by
  // k_attn, dead before k_oproj overwrites z_out. Graph-deterministic.
  u64* maskPk = (u64*)z_out;

  // Wo bf16 aliases the Qb region (dead after k_attn); written post-attn.
  unsigned short* Wob = Qb;

  k_cvt<<<dim3(1024), 256, 0, stream>>>(qx, kx, vx, Wq, Wk, Wv, maskPAD,
                                        cvtb, maskPk);
  k_proj<<<dim3(64, 12, 3), 256, 0, stream>>>(qxb, kxb, vxb, Wqb, Wkb, Wvb,
                                              bq, bk, bv, Qb, Kb, Vt);
  k_attn<<<dim3(8 * 6 * 16, 1, 1), 256, 0, stream>>>(Qb, Kb, Vt, preScores,
                                                     (const u32*)maskPk,
                                                     scores_out, zp);
  k_cvt2<<<dim3(576), 256, 0, stream>>>(Wo, Wob);
  k_oproj<<<dim3(64, 12), 256, 0, stream>>>(zp, Wob, bo, z_out);
}

// Round 15
// 152.884 us; speedup vs baseline: 1.0632x; 1.0632x over previous
//
#include <hip/hip_runtime.h>
#include <hip/hip_bf16.h>

#define B_ 4
#define L_ 1024
#define H_ 12
#define DK_ 64
#define FEA_ 768
#define MASKV (-32767.0f)

typedef __attribute__((ext_vector_type(8))) short bf16x8;
typedef __attribute__((ext_vector_type(4))) short s16x4;
typedef __attribute__((ext_vector_type(4))) float f32x4;
typedef unsigned int u32;

__device__ inline short f2bf(float x) {
  __hip_bfloat16 h = __float2bfloat16(x);   // HW cvt, RNE
  return __builtin_bit_cast(short, h);
}

// sizes (floats)
#define SZX  (4 * 1024 * 768)      // qx/kx/vx each: 3145728
#define SZW  (768 * 768)           // each W: 589824

// ---------------------------------------------------------------------------
// fp32 -> bf16 convert pass: qx,kx,vx,Wq,Wk,Wv -> contiguous bf16 scratch.
// ---------------------------------------------------------------------------
__global__ __launch_bounds__(256) void k_cvt(
    const float* __restrict__ qx, const float* __restrict__ kx,
    const float* __restrict__ vx,
    const float* __restrict__ Wq, const float* __restrict__ Wk,
    const float* __restrict__ Wv,
    unsigned short* __restrict__ dst)
{
  const size_t SZX4 = SZX / 4, SZW4 = SZW / 4;
  const size_t total4 = 3 * SZX4 + 3 * SZW4;
  for (size_t i4 = (size_t)blockIdx.x * 256 + threadIdx.x; i4 < total4;
       i4 += (size_t)gridDim.x * 256) {
    const float* src; size_t o4; size_t db;
    if (i4 < SZX4)               { src = qx; o4 = i4;               db = 0; }
    else if (i4 < 2 * SZX4)      { src = kx; o4 = i4 - SZX4;        db = (size_t)SZX; }
    else if (i4 < 3 * SZX4)      { src = vx; o4 = i4 - 2 * SZX4;    db = 2 * (size_t)SZX; }
    else if (i4 < 3 * SZX4 + SZW4)     { src = Wq; o4 = i4 - 3 * SZX4;            db = 3 * (size_t)SZX; }
    else if (i4 < 3 * SZX4 + 2 * SZW4) { src = Wk; o4 = i4 - 3 * SZX4 - SZW4;     db = 3 * (size_t)SZX + SZW; }
    else                               { src = Wv; o4 = i4 - 3 * SZX4 - 2 * SZW4; db = 3 * (size_t)SZX + 2 * (size_t)SZW; }
    float4 v = ((const float4*)src)[o4];
    s16x4 r = {f2bf(v.x), f2bf(v.y), f2bf(v.z), f2bf(v.w)};
    *(s16x4*)(dst + db + o4 * 4) = r;
  }
}

// ---------------------------------------------------------------------------
// Wo fp32 -> bf16, launched AFTER k_attn; dst aliases the then-dead Qb region.
// ---------------------------------------------------------------------------
__global__ __launch_bounds__(256) void k_cvt2(
    const float* __restrict__ Wo, unsigned short* __restrict__ dst)
{
  size_t i4 = (size_t)blockIdx.x * 256 + threadIdx.x;
  if (i4 < (size_t)SZW / 4) {
    float4 v = ((const float4*)Wo)[i4];
    s16x4 r = {f2bf(v.x), f2bf(v.y), f2bf(v.z), f2bf(v.w)};
    *(s16x4*)(dst + i4 * 4) = r;
  }
}

// ---------------------------------------------------------------------------
// QKV projection (pure bf16, verified R11/R12).
// ---------------------------------------------------------------------------
__global__ __launch_bounds__(256) void k_proj(
    const unsigned short* __restrict__ qxb, const unsigned short* __restrict__ kxb,
    const unsigned short* __restrict__ vxb,
    const unsigned short* __restrict__ Wqb, const unsigned short* __restrict__ Wkb,
    const unsigned short* __restrict__ Wvb,
    const float* __restrict__ bq, const float* __restrict__ bk,
    const float* __restrict__ bv,
    unsigned short* __restrict__ Qb, unsigned short* __restrict__ Kb,
    unsigned short* __restrict__ Vt)
{
  __shared__ short lA[2][64 * 64];
  __shared__ short lB[2][64 * 64];

  const int which = blockIdx.z;
  const unsigned short* __restrict__ Ab = (which == 0) ? qxb : (which == 1) ? kxb : vxb;
  const unsigned short* __restrict__ Wb = (which == 0) ? Wqb : (which == 1) ? Wkb : Wvb;
  const float* __restrict__ bias = (which == 0) ? bq : (which == 1) ? bk : bv;

  const int tid = threadIdx.x;
  const int lane = tid & 63;
  const int wid = tid >> 6;
  const int wr = wid >> 1, wc = wid & 1;
  const int m0 = blockIdx.x * 64;
  const int n0 = blockIdx.y * 64;
  const int g = lane >> 4, qc = lane & 15;
  const int srow = lane >> 3;
  const int spos = lane & 7;

#define PSTAGE(buf, ktof)                                                      \
  {                                                                            \
    _Pragma("unroll")                                                          \
    for (int i_ = 0; i_ < 2; i_++) {                                           \
      int r0_ = wid * 16 + i_ * 8;                                             \
      int row_ = r0_ + srow;                                                   \
      int cs_ = spos ^ (row_ & 7);                                             \
      __builtin_amdgcn_global_load_lds(                                        \
          (const __attribute__((address_space(1))) u32*)(Ab +                  \
              (size_t)(m0 + row_) * FEA_ + (ktof) + cs_ * 8),                  \
          (__attribute__((address_space(3))) u32*)&lA[buf][r0_ * 64],          \
          16, 0, 0);                                                           \
      __builtin_amdgcn_global_load_lds(                                        \
          (const __attribute__((address_space(1))) u32*)(Wb +                  \
              (size_t)(n0 + row_) * FEA_ + (ktof) + cs_ * 8),                  \
          (__attribute__((address_space(3))) u32*)&lB[buf][r0_ * 64],          \
          16, 0, 0);                                                           \
    }                                                                          \
  }

  f32x4 acc[2][2];
#pragma unroll
  for (int i = 0; i < 2; i++)
#pragma unroll
    for (int j = 0; j < 2; j++) acc[i][j] = f32x4{0.f, 0.f, 0.f, 0.f};

  PSTAGE(0, 0);
  asm volatile("s_waitcnt vmcnt(0)" ::: "memory");
  __builtin_amdgcn_s_barrier();

  for (int kt = 0; kt < 12; kt++) {
    const int cur = kt & 1, nxt = cur ^ 1;
    if (kt < 11) PSTAGE(nxt, (kt + 1) * 64);
    __builtin_amdgcn_sched_barrier(0);
    __builtin_amdgcn_s_setprio(1);
#pragma unroll
    for (int s = 0; s < 2; s++) {
      bf16x8 af[2], bfr[2];
#pragma unroll
      for (int i = 0; i < 2; i++) {
        int ar = wr * 32 + i * 16 + qc;
        af[i] = *(const bf16x8*)&lA[cur][ar * 64 + (((s * 4 + g) ^ (ar & 7)) << 3)];
        int br = wc * 32 + i * 16 + qc;
        bfr[i] = *(const bf16x8*)&lB[cur][br * 64 + (((s * 4 + g) ^ (br & 7)) << 3)];
      }
#pragma unroll
      for (int i = 0; i < 2; i++)
#pragma unroll
        for (int j = 0; j < 2; j++)
          acc[i][j] = __builtin_amdgcn_mfma_f32_16x16x32_bf16(af[i], bfr[j], acc[i][j], 0, 0, 0);
    }
    __builtin_amdgcn_s_setprio(0);
    asm volatile("s_waitcnt vmcnt(0)" ::: "memory");
    __builtin_amdgcn_s_barrier();
  }

  const int cn0 = n0 + wc * 32;
  float bv2[2];
#pragma unroll
  for (int j = 0; j < 2; j++) bv2[j] = bias[cn0 + j * 16 + qc];

#pragma unroll
  for (int i = 0; i < 2; i++) {
    int m = m0 + wr * 32 + i * 16 + g * 4;
    int bb = m >> 10;
    int l = m & 1023;
#pragma unroll
    for (int j = 0; j < 2; j++) {
      int n = cn0 + j * 16 + qc;
      int hh = n >> 6, d = n & 63;
      if (which == 2) {
        s16x4 vv = {f2bf(acc[i][j][0] + bv2[j]), f2bf(acc[i][j][1] + bv2[j]),
                    f2bf(acc[i][j][2] + bv2[j]), f2bf(acc[i][j][3] + bv2[j])};
        *(s16x4*)&Vt[(((size_t)bb * H_ + hh) * DK_ + d) * L_ + l] = vv;
      } else {
#pragma unroll
        for (int r = 0; r < 4; r++) {
          unsigned short v = (unsigned short)f2bf(acc[i][j][r] + bv2[j]);
          if (which == 0) {
            Qb[(((size_t)bb * H_ + hh) * L_ + (l + r)) * DK_ + d] = v;
          } else {
            Kb[(((size_t)bb * H_ + hh) * L_ + (l + r)) * DK_ + d] = v;
          }
        }
      }
    }
  }
#undef PSTAGE
}

// ---------------------------------------------------------------------------
// Fused attention v9 (verified R13, BEST): R8 schedule + coalesced
// ps/mask/scores lanes (4 rows x 256B contiguous per instruction). QK^T
// bridged MFMA-layout -> coalesced-layout via wave-private LDS bounce (lU);
// lP aliases the head of lU.
// ---------------------------------------------------------------------------
__global__ __launch_bounds__(256, 3) void k_attn(
    const unsigned short* __restrict__ Qb, const unsigned short* __restrict__ Kb,
    const unsigned short* __restrict__ Vt,
    const float* __restrict__ preScores, const int* __restrict__ maskPAD,
    float* __restrict__ scoresOut, unsigned short* __restrict__ zp)
{
  __shared__ short lK[2][64 * 64];
  __shared__ short lV[2][64 * 64];
  __shared__ float lU[4][1120];   // per wave: st spill 16x68 f32 (lP aliases
                                  // head), [1088..1103] row sums

  const int tid = threadIdx.x, lane = tid & 63, wid = tid >> 6;
  const int bi = blockIdx.x;
  const int slot = bi >> 3;
  const int bh_i = (bi & 7) * 6 + (slot >> 4);
  const int qt = slot & 15;
  const int b = bh_i / H_;
  const int h = bh_i % H_;
  const int q0 = qt * 64;
  const int g = lane >> 4, qr = lane & 15;
  const int qrow = q0 + wid * 16 + qr;         // MFMA-layout row
  const int rhi = lane >> 4, klo = lane & 15;  // coalesced roles
  const int rowCg = q0 + wid * 16 + rhi;       // coalesced-layout global row

  const size_t bh = (size_t)b * H_ + h;
  const unsigned short* __restrict__ Kbh = Kb + bh * L_ * DK_;
  const unsigned short* __restrict__ Vbh = Vt + bh * DK_ * L_;

  float* lSw = &lU[wid][0];
  short* lPw = (short*)&lU[wid][0];
  float* lLw = &lU[wid][1088];

  const int srow = lane >> 3;
  const int spos = lane & 7;

#define STAGE_KV(buf, kv0)                                                     \
  {                                                                            \
    _Pragma("unroll")                                                          \
    for (int i_ = 0; i_ < 2; i_++) {                                           \
      int r0_ = wid * 16 + i_ * 8;                                             \
      int row_ = r0_ + srow;                                                   \
      int cs_ = spos ^ (row_ & 7);                                             \
      __builtin_amdgcn_global_load_lds(                                        \
          (const __attribute__((address_space(1))) u32*)(Kbh +                 \
              (size_t)((kv0) + row_) * DK_ + cs_ * 8),                         \
          (__attribute__((address_space(3))) u32*)&lK[buf][r0_ * 64],          \
          16, 0, 0);                                                           \
      __builtin_amdgcn_global_load_lds(                                        \
          (const __attribute__((address_space(1))) u32*)(Vbh +                 \
              (size_t)row_ * L_ + (kv0) + cs_ * 8),                            \
          (__attribute__((address_space(3))) u32*)&lV[buf][r0_ * 64],          \
          16, 0, 0);                                                           \
    }                                                                          \
  }

  bf16x8 qf[2];
#pragma unroll
  for (int s = 0; s < 2; s++)
    qf[s] = *(const bf16x8*)(Qb + (bh * L_ + qrow) * DK_ + s * 32 + g * 8);

  f32x4 o[4];
#pragma unroll
  for (int i = 0; i < 4; i++) o[i] = f32x4{0.f, 0.f, 0.f, 0.f};
  float psum[4] = {0.f, 0.f, 0.f, 0.f};   // per coalesced row (4j+rhi)

  const size_t psCbase = (bh * L_ + rowCg) * L_ + klo * 4;
  const size_t mkCbase = ((size_t)b * L_ + rowCg) * L_ + klo * 4;

  STAGE_KV(0, 0);
  __builtin_amdgcn_sched_barrier(0);
  float4 psn[4];
  int4 mkn[4];
#pragma unroll
  for (int j = 0; j < 4; j++) {
    psn[j] = *(const float4*)(preScores + psCbase + j * 4096);
    mkn[j] = *(const int4*)(maskPAD + mkCbase + j * 4096);
  }
  asm volatile("s_waitcnt vmcnt(8)" ::: "memory");
  __builtin_amdgcn_s_barrier();

  for (int kt = 0; kt < 16; kt++) {
    const int kv0 = kt * 64;
    const int cur = kt & 1, nxt = cur ^ 1;

    if (kt < 15) {
      STAGE_KV(nxt, kv0 + 64);
    }
    __builtin_amdgcn_sched_barrier(0);

    float4 psc[4]; int4 mkc[4];
#pragma unroll
    for (int j = 0; j < 4; j++) { psc[j] = psn[j]; mkc[j] = mkn[j]; }
    if (kt < 15) {
#pragma unroll
      for (int j = 0; j < 4; j++) {
        psn[j] = *(const float4*)(preScores + psCbase + kv0 + 64 + j * 4096);
        mkn[j] = *(const int4*)(maskPAD + mkCbase + kv0 + 64 + j * 4096);
      }
    }

    // S^T = K . Q^T from LDS (MFMA layout)
    f32x4 st[4];
#pragma unroll
    for (int i = 0; i < 4; i++) st[i] = f32x4{0.f, 0.f, 0.f, 0.f};
    __builtin_amdgcn_s_setprio(1);
#pragma unroll
    for (int s = 0; s < 2; s++) {
#pragma unroll
      for (int i = 0; i < 4; i++) {
        int kr = i * 16 + qr;
        bf16x8 kf = *(const bf16x8*)&lK[cur][kr * 64 + (((s * 4 + g) ^ (kr & 7)) << 3)];
        st[i] = __builtin_amdgcn_mfma_f32_16x16x32_bf16(kf, qf[s], st[i], 0, 0, 0);
      }
    }
    __builtin_amdgcn_s_setprio(0);

    // bridge MFMA layout -> coalesced layout through wave-private LDS
#pragma unroll
    for (int i = 0; i < 4; i++)
      *(f32x4*)&lSw[qr * 68 + i * 16 + g * 4] = st[i];
    f32x4 stc[4];
#pragma unroll
    for (int j = 0; j < 4; j++)
      stc[j] = *(const f32x4*)&lSw[(4 * j + rhi) * 68 + klo * 4];

    // coalesced: scale + ps + mask; 256B-contiguous scores store; exp;
    // per-row psum; pack p into lP (aliases lS head — all stc reads done).
#pragma unroll
    for (int j = 0; j < 4; j++) {
      float4 sv;
      sv.x = (mkc[j].x == 0) ? MASKV : stc[j][0] * 0.125f + psc[j].x;
      sv.y = (mkc[j].y == 0) ? MASKV : stc[j][1] * 0.125f + psc[j].y;
      sv.z = (mkc[j].z == 0) ? MASKV : stc[j][2] * 0.125f + psc[j].z;
      sv.w = (mkc[j].w == 0) ? MASKV : stc[j][3] * 0.125f + psc[j].w;
      *(float4*)(scoresOut + psCbase + kv0 + j * 4096) = sv;
      float p0 = __expf(sv.x);
      float p1 = __expf(sv.y);
      float p2 = __expf(sv.z);
      float p3 = __expf(sv.w);
      psum[j] += (p0 + p1) + (p2 + p3);
      s16x4 pw = {f2bf(p0), f2bf(p1), f2bf(p2), f2bf(p3)};
      int rL = 4 * j + rhi;
      int c = klo >> 1, sub = (klo & 1) * 4;
      *(s16x4*)&lPw[rL * 64 + ((c ^ (rL & 7)) << 3) + sub] = pw;
    }

    // O^T += Vt_strip . P^T from LDS
    __builtin_amdgcn_s_setprio(1);
#pragma unroll
    for (int s = 0; s < 2; s++) {
      bf16x8 pf = *(const bf16x8*)&lPw[qr * 64 + (((s * 4 + g) ^ (qr & 7)) << 3)];
#pragma unroll
      for (int i = 0; i < 4; i++) {
        int vr = i * 16 + qr;
        bf16x8 vf = *(const bf16x8*)&lV[cur][vr * 64 + (((s * 4 + g) ^ (vr & 7)) << 3)];
        o[i] = __builtin_amdgcn_mfma_f32_16x16x32_bf16(vf, pf, o[i], 0, 0, 0);
      }
    }
    __builtin_amdgcn_s_setprio(0);

    asm volatile("s_waitcnt vmcnt(12)" ::: "memory");
    __builtin_amdgcn_s_barrier();
  }

  // per-row sums: reduce over the 16 klo lanes, publish via lLw, normalize.
#pragma unroll
  for (int j = 0; j < 4; j++) {
    float v = psum[j];
    v += __shfl_xor(v, 1);
    v += __shfl_xor(v, 2);
    v += __shfl_xor(v, 4);
    v += __shfl_xor(v, 8);
    if (klo == 0) lLw[4 * j + rhi] = v;
  }
  float inv = 1.f / lLw[qr];
  size_t zr = ((size_t)b * L_ + qrow) * FEA_ + (size_t)h * DK_;
#pragma unroll
  for (int i = 0; i < 4; i++) {
    s16x4 zw = {f2bf(o[i][0] * inv), f2bf(o[i][1] * inv),
                f2bf(o[i][2] * inv), f2bf(o[i][3] * inv)};
    *(s16x4*)((unsigned short*)zp + zr + i * 16 + g * 4) = zw;
  }
#undef STAGE_KV
}

// ---------------------------------------------------------------------------
// Output projection (pure bf16, verified R12).
// ---------------------------------------------------------------------------
__global__ __launch_bounds__(256) void k_oproj(
    const unsigned short* __restrict__ zp,
    const unsigned short* __restrict__ Wob, const float* __restrict__ bo,
    float* __restrict__ out)
{
  __shared__ short lA[2][64 * 64];
  __shared__ short lB[2][64 * 64];

  const int tid = threadIdx.x;
  const int lane = tid & 63;
  const int wid = tid >> 6;
  const int wr = wid >> 1, wc = wid & 1;
  const int m0 = blockIdx.x * 64;
  const int n0 = blockIdx.y * 64;
  const int g = lane >> 4, qc = lane & 15;
  const int srow = lane >> 3;
  const int spos = lane & 7;

#define OSTAGE(buf, ktof)                                                      \
  {                                                                            \
    _Pragma("unroll")                                                          \
    for (int i_ = 0; i_ < 2; i_++) {                                           \
      int r0_ = wid * 16 + i_ * 8;                                             \
      int row_ = r0_ + srow;                                                   \
      int cs_ = spos ^ (row_ & 7);                                             \
      __builtin_amdgcn_global_load_lds(                                        \
          (const __attribute__((address_space(1))) u32*)(zp +                  \
              (size_t)(m0 + row_) * FEA_ + (ktof) + cs_ * 8),                  \
          (__attribute__((address_space(3))) u32*)&lA[buf][r0_ * 64],          \
          16, 0, 0);                                                           \
      __builtin_amdgcn_global_load_lds(                                        \
          (const __attribute__((address_space(1))) u32*)(Wob +                 \
              (size_t)(n0 + row_) * FEA_ + (ktof) + cs_ * 8),                  \
          (__attribute__((address_space(3))) u32*)&lB[buf][r0_ * 64],          \
          16, 0, 0);                                                           \
    }                                                                          \
  }

  f32x4 acc[2][2];
#pragma unroll
  for (int i = 0; i < 2; i++)
#pragma unroll
    for (int j = 0; j < 2; j++) acc[i][j] = f32x4{0.f, 0.f, 0.f, 0.f};

  OSTAGE(0, 0);
  asm volatile("s_waitcnt vmcnt(0)" ::: "memory");
  __builtin_amdgcn_s_barrier();

  for (int kt = 0; kt < 12; kt++) {
    const int cur = kt & 1, nxt = cur ^ 1;
    if (kt < 11) OSTAGE(nxt, (kt + 1) * 64);
    __builtin_amdgcn_sched_barrier(0);
    __builtin_amdgcn_s_setprio(1);
#pragma unroll
    for (int s = 0; s < 2; s++) {
      bf16x8 af[2], bfr[2];
#pragma unroll
      for (int i = 0; i < 2; i++) {
        int ar = wr * 32 + i * 16 + qc;
        af[i] = *(const bf16x8*)&lA[cur][ar * 64 + (((s * 4 + g) ^ (ar & 7)) << 3)];
        int br = wc * 32 + i * 16 + qc;
        bfr[i] = *(const bf16x8*)&lB[cur][br * 64 + (((s * 4 + g) ^ (br & 7)) << 3)];
      }
#pragma unroll
      for (int i = 0; i < 2; i++)
#pragma unroll
        for (int j = 0; j < 2; j++)
          acc[i][j] = __builtin_amdgcn_mfma_f32_16x16x32_bf16(af[i], bfr[j], acc[i][j], 0, 0, 0);
    }
    __builtin_amdgcn_s_setprio(0);
    asm volatile("s_waitcnt vmcnt(0)" ::: "memory");
    __builtin_amdgcn_s_barrier();
  }

  const int cn0 = n0 + wc * 32;
  float bv2[2];
#pragma unroll
  for (int j = 0; j < 2; j++) bv2[j] = bo[cn0 + j * 16 + qc];

#pragma unroll
  for (int i = 0; i < 2; i++) {
    int m = m0 + wr * 32 + i * 16 + g * 4;
#pragma unroll
    for (int j = 0; j < 2; j++) {
      int n = cn0 + j * 16 + qc;
#pragma unroll
      for (int r = 0; r < 4; r++) {
        out[(size_t)(m + r) * FEA_ + n] = acc[i][j][r] + bv2[j];
      }
    }
  }
#undef OSTAGE
}

extern "C" void kernel_launch(void* const* d_in, const int* in_sizes, int n_in,
                              void* d_out, int out_size, void* d_ws, size_t ws_size,
                              hipStream_t stream) {
  const float* qx = (const float*)d_in[0];
  const float* kx = (const float*)d_in[1];
  const float* vx = (const float*)d_in[2];
  const float* preScores = (const float*)d_in[3];
  const int* maskPAD = (const int*)d_in[4];
  const float* Wq = (const float*)d_in[5];
  const float* bq = (const float*)d_in[6];
  const float* Wk = (const float*)d_in[7];
  const float* bk = (const float*)d_in[8];
  const float* Wv = (const float*)d_in[9];
  const float* bv = (const float*)d_in[10];
  const float* Wo = (const float*)d_in[11];
  const float* bo = (const float*)d_in[12];

  float* z_out = (float*)d_out;
  float* scores_out = z_out + (size_t)B_ * L_ * FEA_;

  unsigned short* Qb = (unsigned short*)d_ws;
  unsigned short* Kb = Qb + (size_t)B_ * H_ * L_ * DK_;
  unsigned short* Vt = Kb + (size_t)B_ * H_ * L_ * DK_;
  unsigned short* zp = Vt + (size_t)B_ * H_ * L_ * DK_;

  unsigned short* cvtb = (unsigned short*)(scores_out + (50331648 - 5603328));
  const unsigned short* qxb = cvtb;
  const unsigned short* kxb = cvtb + (size_t)SZX;
  const unsigned short* vxb = cvtb + 2 * (size_t)SZX;
  const unsigned short* Wqb = cvtb + 3 * (size_t)SZX;
  const unsigned short* Wkb = cvtb + 3 * (size_t)SZX + (size_t)SZW;
  const unsigned short* Wvb = cvtb + 3 * (size_t)SZX + 2 * (size_t)SZW;

  unsigned short* Wob = Qb;   // dead after k_attn

  k_cvt<<<dim3(1024), 256, 0, stream>>>(qx, kx, vx, Wq, Wk, Wv, cvtb);
  k_proj<<<dim3(64, 12, 3), 256, 0, stream>>>(qxb, kxb, vxb, Wqb, Wkb, Wvb,
                                              bq, bk, bv, Qb, Kb, Vt);
  k_attn<<<dim3(8 * 6 * 16, 1, 1), 256, 0, stream>>>(Qb, Kb, Vt, preScores,
                                                     maskPAD, scores_out, zp);
  k_cvt2<<<dim3(576), 256, 0, stream>>>(Wo, Wob);
  k_oproj<<<dim3(64, 12), 256, 0, stream>>>(zp, Wob, bo, z_out);
}